// Round 12
// baseline (327.298 us; speedup 1.0000x reference)
//
#include <hip/hip_runtime.h>
#include <math.h>

#define NN 100000
#define NE 1600000
#define DIM 128
#define NBKT 196        // ceil(100000/512) coarse buckets (dst>>9)
#define BSTRIDE 9216    // per-bucket arena stride
#define PA_EPB 4096
#define PA_GRID 391     // ceil(NE/PA_EPB)
#define WCVT_B 24       // 3 layers * 2048 entries / 256
#define GEMB 3125       // gemm blocks (32-row tiles), 3125*32 == NN
#define NGATB 3125      // gatherpool blocks

typedef __attribute__((ext_vector_type(4))) float f32x4;
typedef __attribute__((ext_vector_type(2))) float f32x2;

// ---- fp8 e4m3 helpers ----
__device__ __forceinline__ unsigned int pk4(float a, float b, float c, float d) {
    unsigned int w = __builtin_amdgcn_cvt_pk_fp8_f32(a, b, 0u, false);
    return __builtin_amdgcn_cvt_pk_fp8_f32(c, d, w, true);
}
__device__ __forceinline__ void accp8(unsigned int w, float* a) {
    f32x2 lo = __builtin_amdgcn_cvt_pk_f32_fp8(w, false);
    f32x2 hi = __builtin_amdgcn_cvt_pk_f32_fp8(w, true);
    a[0] += lo[0]; a[1] += lo[1]; a[2] += hi[0]; a[3] += hi[1];
}
__device__ __forceinline__ void unp8(unsigned int w, float* a) {
    f32x2 lo = __builtin_amdgcn_cvt_pk_f32_fp8(w, false);
    f32x2 hi = __builtin_amdgcn_cvt_pk_f32_fp8(w, true);
    a[0] = lo[0]; a[1] = lo[1]; a[2] = hi[0]; a[3] = hi[1];
}

// ---------------- init arena cursors ----------------
__global__ void k_initcur(int* __restrict__ gcursor) {
    int i = threadIdx.x;
    if (i < NBKT) gcursor[i] = i * BSTRIDE;
}

// =======================================================================
// k_pawc: [0,PA_GRID) CSR passA | [PA_GRID,+WCVT_B) W1/W2/W3 -> fp8 images
// W image layout (per layer, 16384 B): byte = col*128 + ((kc ^ (col&15))*8)
//   (col&15 distinct per 16-lane MFMA group -> full 32-bank coverage)
// =======================================================================
__global__ __launch_bounds__(256) void k_pawc(const float* __restrict__ W1,
                                              const float* __restrict__ W2,
                                              const float* __restrict__ W3,
                                              const int* __restrict__ src,
                                              const int* __restrict__ dst,
                                              int* __restrict__ gcursor,
                                              unsigned int* __restrict__ epk,
                                              char* __restrict__ Wg8) {
    __shared__ __align__(16) char smem[24768];
    const int tid = threadIdx.x;
    const int bid = blockIdx.x;

    if (bid < PA_GRID) {
        int* hist = (int*)smem;                         // 784 B
        int* offs = (int*)(smem + 784);
        int* gbase = (int*)(smem + 1568);
        int* lcur = (int*)(smem + 2352);
        int* sc   = (int*)(smem + 3136);                // 1024 B
        unsigned int* stg = (unsigned int*)(smem + 4160);     // 16 KB
        unsigned char* stgb = (unsigned char*)(smem + 20544); // 4 KB
        const int e0 = bid * PA_EPB;
        const int ecnt = min(PA_EPB, NE - e0);

        for (int i = tid; i < NBKT; i += 256) hist[i] = 0;
        __syncthreads();
        for (int i = tid; i < ecnt; i += 256)
            atomicAdd(&hist[dst[e0 + i] >> 9], 1);
        __syncthreads();
        int v = (tid < NBKT) ? hist[tid] : 0;
        sc[tid] = v;
        __syncthreads();
        for (int off = 1; off < 256; off <<= 1) {
            int t = (tid >= off) ? sc[tid - off] : 0;
            __syncthreads();
            sc[tid] += t;
            __syncthreads();
        }
        if (tid < NBKT) {
            offs[tid] = sc[tid] - v;
            lcur[tid] = sc[tid] - v;
            gbase[tid] = v ? atomicAdd(&gcursor[tid], v) : 0;
        }
        __syncthreads();
        for (int i = tid; i < ecnt; i += 256) {
            int d = dst[e0 + i];
            int s = src[e0 + i];
            int b = d >> 9;
            int pos = atomicAdd(&lcur[b], 1);
            stg[pos] = ((unsigned)(d & 511) << 17) | (unsigned)s;
            stgb[pos] = (unsigned char)b;
        }
        __syncthreads();
        for (int i = tid; i < ecnt; i += 256) {
            int b = stgb[i];
            epk[gbase[b] + (i - offs[b])] = stg[i];
        }
    } else {
        int idx2 = (bid - PA_GRID) * 256 + tid;   // 0 .. 6143
        if (idx2 < 3 * 2048) {
            int layer = idx2 >> 11, r = idx2 & 2047;
            const float* W = layer == 0 ? W1 : (layer == 1 ? W2 : W3);
            int col = r >> 4;    // 0..127
            int kc  = r & 15;    // k-chunk of 8
            uint2 d;
            d.x = pk4(W[(kc * 8 + 0) * DIM + col], W[(kc * 8 + 1) * DIM + col],
                      W[(kc * 8 + 2) * DIM + col], W[(kc * 8 + 3) * DIM + col]);
            d.y = pk4(W[(kc * 8 + 4) * DIM + col], W[(kc * 8 + 5) * DIM + col],
                      W[(kc * 8 + 6) * DIM + col], W[(kc * 8 + 7) * DIM + col]);
            *reinterpret_cast<uint2*>(Wg8 + layer * 16384 + col * 128 + ((kc ^ (col & 15)) * 8)) = d;
        }
    }
}

// ---------------- passB: per-bucket fine CSR (rowptr/deg/dinv + sorted esrc) ----------------
__global__ __launch_bounds__(256) void k_passB(const unsigned int* __restrict__ epk,
                                               const int* __restrict__ gcursor,
                                               int* __restrict__ rowptr,
                                               int* __restrict__ degp,
                                               float* __restrict__ dinv,
                                               int* __restrict__ esrc) {
    __shared__ int cnt[512];
    __shared__ int offs[512];
    __shared__ int lcur[512];
    __shared__ int sc[256];
    __shared__ int stg[BSTRIDE];
    const int b = blockIdx.x, tid = threadIdx.x;
    const int n0 = b << 9;
    const int nnb = min(512, NN - n0);
    const int ebase = b * BSTRIDE;
    const int ecnt = min(gcursor[b] - ebase, BSTRIDE);

    for (int i = tid; i < 512; i += 256) cnt[i] = 0;
    __syncthreads();
    for (int i = tid; i < ecnt; i += 256)
        atomicAdd(&cnt[epk[ebase + i] >> 17], 1);
    __syncthreads();
    int a0 = cnt[2 * tid], a1 = cnt[2 * tid + 1];
    sc[tid] = a0 + a1;
    __syncthreads();
    for (int off = 1; off < 256; off <<= 1) {
        int t = (tid >= off) ? sc[tid - off] : 0;
        __syncthreads();
        sc[tid] += t;
        __syncthreads();
    }
    int base = sc[tid] - (a0 + a1);
    offs[2 * tid] = base;
    offs[2 * tid + 1] = base + a0;
    lcur[2 * tid] = base;
    lcur[2 * tid + 1] = base + a0;
    __syncthreads();
    for (int ln = tid; ln < nnb; ln += 256) {
        int dg = cnt[ln];
        rowptr[n0 + ln] = ebase + offs[ln];
        degp[n0 + ln] = dg;
        dinv[n0 + ln] = rsqrtf(1.f + (float)dg);
    }
    for (int i = tid; i < ecnt; i += 256) {
        unsigned p = epk[ebase + i];
        int pos = atomicAdd(&lcur[p >> 17], 1);
        stg[pos] = (int)(p & 0x1FFFFu);
    }
    __syncthreads();
    for (int i = tid; i < ecnt; i += 256)
        esrc[ebase + i] = stg[i];
}

// =======================================================================
// k_gemm<DENSE>: 32-row tile.
//  DENSE:  X = fp8(x row)                       (layer 1; bias unused)
//  !DENSE: X = relu(dinv*(g[n] + sum g[src]) + bias)   (g is dinv-scaled)
//  then fp8 MFMA (W image pure-copied to LDS) -> out g = h*dinv (fp8)
//  LDS: Wt8 16 KB + Xb8 4 KB = 20 KB -> 8 blocks/CU
// =======================================================================
template <bool DENSE>
__global__ __launch_bounds__(256, 8) void k_gemm(const float* __restrict__ x,
                                                 const uint4* __restrict__ g8,
                                                 const int* __restrict__ esrc,
                                                 const int* __restrict__ rowptr,
                                                 const int* __restrict__ degp,
                                                 const float* __restrict__ dinv,
                                                 const float* __restrict__ bias,
                                                 const char* __restrict__ Wgl,
                                                 uint4* __restrict__ out8) {
    __shared__ __align__(16) char Wt8[16384];
    __shared__ __align__(16) char Xb8[4096];
    const int tid = threadIdx.x;
    const int rb = blockIdx.x * 32;

    // stage pre-swizzled fp8 W image (pure copy)
    for (int idx = tid; idx < 1024; idx += 256)
        reinterpret_cast<uint4*>(Wt8)[idx] = reinterpret_cast<const uint4*>(Wgl)[idx];

    // ---- X phase: 32 rows x 8 lanes ----
    {
        const int row = tid >> 3;
        const int c = tid & 7;
        const int grow = rb + row;    // GEMB*32 == NN exactly
        float r[16];
        if (DENSE) {
            const float4* xp = reinterpret_cast<const float4*>(x + (size_t)grow * DIM + c * 16);
            float4 v0 = xp[0], v1 = xp[1], v2 = xp[2], v3 = xp[3];
            r[0] = v0.x;  r[1] = v0.y;  r[2] = v0.z;  r[3] = v0.w;
            r[4] = v1.x;  r[5] = v1.y;  r[6] = v1.z;  r[7] = v1.w;
            r[8] = v2.x;  r[9] = v2.y;  r[10] = v2.z; r[11] = v2.w;
            r[12] = v3.x; r[13] = v3.y; r[14] = v3.z; r[15] = v3.w;
        } else {
            float a[16];
            uint4 sv = g8[(size_t)grow * 8 + c];
            unp8(sv.x, a); unp8(sv.y, a + 4); unp8(sv.z, a + 8); unp8(sv.w, a + 12);
            int j0 = rowptr[grow];
            int j1 = j0 + degp[grow];
            int j = j0;
            for (; j + 4 <= j1; j += 4) {
                int s0 = esrc[j], s1 = esrc[j + 1], s2 = esrc[j + 2], s3 = esrc[j + 3];
                uint4 v0 = g8[(size_t)s0 * 8 + c];
                uint4 v1 = g8[(size_t)s1 * 8 + c];
                uint4 v2 = g8[(size_t)s2 * 8 + c];
                uint4 v3 = g8[(size_t)s3 * 8 + c];
                accp8(v0.x, a); accp8(v0.y, a + 4); accp8(v0.z, a + 8); accp8(v0.w, a + 12);
                accp8(v1.x, a); accp8(v1.y, a + 4); accp8(v1.z, a + 8); accp8(v1.w, a + 12);
                accp8(v2.x, a); accp8(v2.y, a + 4); accp8(v2.z, a + 8); accp8(v2.w, a + 12);
                accp8(v3.x, a); accp8(v3.y, a + 4); accp8(v3.z, a + 8); accp8(v3.w, a + 12);
            }
            for (; j < j1; ++j) {
                uint4 v = g8[(size_t)esrc[j] * 8 + c];
                accp8(v.x, a); accp8(v.y, a + 4); accp8(v.z, a + 8); accp8(v.w, a + 12);
            }
            float di = dinv[grow];
            const float4* bp = reinterpret_cast<const float4*>(bias + c * 16);
#pragma unroll
            for (int q = 0; q < 4; ++q) {
                float4 bb = bp[q];
                r[q * 4 + 0] = fmaxf(fmaf(a[q * 4 + 0], di, bb.x), 0.f);
                r[q * 4 + 1] = fmaxf(fmaf(a[q * 4 + 1], di, bb.y), 0.f);
                r[q * 4 + 2] = fmaxf(fmaf(a[q * 4 + 2], di, bb.z), 0.f);
                r[q * 4 + 3] = fmaxf(fmaf(a[q * 4 + 3], di, bb.w), 0.f);
            }
        }
        uint4 o;
        o.x = pk4(r[0], r[1], r[2], r[3]);
        o.y = pk4(r[4], r[5], r[6], r[7]);
        o.z = pk4(r[8], r[9], r[10], r[11]);
        o.w = pk4(r[12], r[13], r[14], r[15]);
        *reinterpret_cast<uint4*>(&Xb8[row * 128 + ((c ^ (row & 7)) * 16)]) = o;
    }
    __syncthreads();

    // ---- MFMA phase: wave w -> node-group (w&1), col-tiles (w>>1)*4.. ----
    const int lane = tid & 63;
    const int w    = tid >> 6;
    const int l15  = lane & 15;
    const int kg   = lane >> 4;
    const int ng   = w & 1;
    const int ctb  = (w >> 1) * 4;
    f32x4 acc[4];
#pragma unroll
    for (int i = 0; i < 4; ++i) acc[i] = (f32x4){0.f, 0.f, 0.f, 0.f};
    const int arow = ng * 16 + l15;
#pragma unroll
    for (int ks = 0; ks < 4; ++ks) {
        int kc = ks * 4 + kg;
        long xf = *reinterpret_cast<const long*>(
            &Xb8[arow * 128 + (((kc >> 1) ^ (arow & 7)) * 16 + (kc & 1) * 8)]);
#pragma unroll
        for (int i = 0; i < 4; ++i) {
            int col = (ctb + i) * 16 + l15;
            long wf = *reinterpret_cast<const long*>(&Wt8[col * 128 + ((kc ^ (col & 15)) * 8)]);
            acc[i] = __builtin_amdgcn_mfma_f32_16x16x32_fp8_fp8(wf, xf, acc[i], 0, 0, 0);
        }
    }
    __syncthreads();

    // ---- epilogue: *dinv, pack fp8, swizzled stage, coalesced out ----
    unsigned int* Xo = reinterpret_cast<unsigned int*>(Xb8);
    const int node = ng * 16 + l15;
    float dv = dinv[rb + node];
#pragma unroll
    for (int i = 0; i < 4; ++i) {
        int ct = ctb + i;
        unsigned int d = pk4(acc[i][0] * dv, acc[i][1] * dv, acc[i][2] * dv, acc[i][3] * dv);
        Xo[node * 32 + ((ct * 4 + kg) ^ ((node & 7) << 2))] = d;
    }
    __syncthreads();
    {
        int row = tid >> 3, kc = tid & 7;   // 256 threads == 32*8 exactly
        out8[(size_t)(rb + row) * 8 + kc] =
            reinterpret_cast<const uint4*>(Xo)[row * 8 + (kc ^ (row & 7))];
    }
}

// ------- final gather + bias + relu + mean-pool partials -------
__global__ __launch_bounds__(256) void k_gatherpool(const uint4* __restrict__ g8,
                                                    const int* __restrict__ esrc,
                                                    const int* __restrict__ rowptr,
                                                    const int* __restrict__ degp,
                                                    const float* __restrict__ dinv,
                                                    const float* __restrict__ bias,
                                                    float* __restrict__ ppart) {
    int t = blockIdx.x * 256 + threadIdx.x;
    int n = t >> 3;
    int c = t & 7;
    int j0 = rowptr[n], j1 = j0 + degp[n];
    float a[16];
    uint4 sv = g8[(size_t)n * 8 + c];
    unp8(sv.x, a); unp8(sv.y, a + 4); unp8(sv.z, a + 8); unp8(sv.w, a + 12);
    int j = j0;
    for (; j + 4 <= j1; j += 4) {
        int s0 = esrc[j], s1 = esrc[j + 1], s2 = esrc[j + 2], s3 = esrc[j + 3];
        uint4 v0 = g8[(size_t)s0 * 8 + c];
        uint4 v1 = g8[(size_t)s1 * 8 + c];
        uint4 v2 = g8[(size_t)s2 * 8 + c];
        uint4 v3 = g8[(size_t)s3 * 8 + c];
        accp8(v0.x, a); accp8(v0.y, a + 4); accp8(v0.z, a + 8); accp8(v0.w, a + 12);
        accp8(v1.x, a); accp8(v1.y, a + 4); accp8(v1.z, a + 8); accp8(v1.w, a + 12);
        accp8(v2.x, a); accp8(v2.y, a + 4); accp8(v2.z, a + 8); accp8(v2.w, a + 12);
        accp8(v3.x, a); accp8(v3.y, a + 4); accp8(v3.z, a + 8); accp8(v3.w, a + 12);
    }
    for (; j < j1; ++j) {
        uint4 v = g8[(size_t)esrc[j] * 8 + c];
        accp8(v.x, a); accp8(v.y, a + 4); accp8(v.z, a + 8); accp8(v.w, a + 12);
    }
    float di = dinv[n];
    const float4* bp = reinterpret_cast<const float4*>(bias + c * 16);
    __shared__ float red[32][132];
    int slot = threadIdx.x >> 3;
#pragma unroll
    for (int q = 0; q < 4; ++q) {
        float4 bb = bp[q];
        red[slot][c * 16 + q * 4 + 0] = fmaxf(fmaf(a[q * 4 + 0], di, bb.x), 0.f);
        red[slot][c * 16 + q * 4 + 1] = fmaxf(fmaf(a[q * 4 + 1], di, bb.y), 0.f);
        red[slot][c * 16 + q * 4 + 2] = fmaxf(fmaf(a[q * 4 + 2], di, bb.z), 0.f);
        red[slot][c * 16 + q * 4 + 3] = fmaxf(fmaf(a[q * 4 + 3], di, bb.w), 0.f);
    }
    __syncthreads();
    if (threadIdx.x < 128) {
        float s = 0.f;
#pragma unroll
        for (int sl = 0; sl < 32; ++sl) s += red[sl][threadIdx.x];
        ppart[blockIdx.x * 128 + threadIdx.x] = s;
    }
}

// ---------------- pool partial reduce: 3125x128 -> 128x128 ----------------
__global__ void k_red1(const float* __restrict__ ppart, float* __restrict__ pp2) {
    int j = blockIdx.x;
    int c = threadIdx.x;
    int p0 = j * 25, p1 = min(p0 + 25, NGATB);
    float s = 0.f;
    for (int p = p0; p < p1; ++p) s += ppart[p * 128 + c];
    pp2[j * 128 + c] = s;
}

// ---------------- final: reduce + fc + softmax ----------------
__global__ void k_final(const float* __restrict__ pp2, const float* __restrict__ fc_w,
                        const float* __restrict__ fc_b, float* __restrict__ out) {
    __shared__ float part[4][DIM];
    int c = threadIdx.x;
    float s = 0.f;
    for (int j = 0; j < 128; ++j) s += pp2[j * 128 + c];
    float p = s * (1.f / NN);
    for (int j = 0; j < 4; ++j) part[j][c] = p * fc_w[c * 4 + j];
    __syncthreads();
    if (c == 0) {
        float l[4];
        for (int j = 0; j < 4; ++j) {
            float acc = fc_b[j];
            for (int i = 0; i < DIM; ++i) acc += part[j][i];
            l[j] = acc;
        }
        float m = fmaxf(fmaxf(l[0], l[1]), fmaxf(l[2], l[3]));
        float e[4], Z = 0.f;
        for (int j = 0; j < 4; ++j) { e[j] = expf(l[j] - m); Z += e[j]; }
        for (int j = 0; j < 4; ++j) out[j] = e[j] / Z;
    }
}

extern "C" void kernel_launch(void* const* d_in, const int* in_sizes, int n_in,
                              void* d_out, int out_size, void* d_ws, size_t ws_size,
                              hipStream_t stream) {
    const float* x   = (const float*)d_in[0];
    const int*   ei  = (const int*)d_in[1];
    const float* W1  = (const float*)d_in[2];
    const float* b1  = (const float*)d_in[3];
    const float* W2  = (const float*)d_in[4];
    const float* b2  = (const float*)d_in[5];
    const float* W3  = (const float*)d_in[6];
    const float* b3  = (const float*)d_in[7];
    const float* fcw = (const float*)d_in[8];
    const float* fcb = (const float*)d_in[9];
    float* out = (float*)d_out;

    char* ws = (char*)d_ws;
    uint4* A8a     = (uint4*)(ws);                       // 12,800,000 B (fp8 g)
    uint4* A8b     = (uint4*)(ws + 12800000);            // 12,800,000 B
    float* dinv    = (float*)(ws + 25600000);            //    400,000 B
    int*   rowptr  = (int*)  (ws + 26000000);            //    400,000 B
    int*   degp    = (int*)  (ws + 26400000);            //    400,000 B
    int*   esrc    = (int*)  (ws + 26800000);            //  7,225,344 B
    unsigned int* epk = (unsigned int*)(ws + 34025344);  //  7,225,344 B
    int*   gcursor = (int*)  (ws + 41250688);            //      1,024 B
    float* ppart   = (float*)(ws + 41251712);            //  1,600,000 B
    float* pp2     = (float*)(ws + 42851712);            //     65,536 B
    char*  Wg8     = (char*) (ws + 42917248);            //     49,152 B (3 fp8 W images)

    const int* src = ei;
    const int* dst = ei + NE;

    // ---- CSR build + W fp8 images ----
    k_initcur<<<1, 256, 0, stream>>>(gcursor);
    k_pawc<<<PA_GRID + WCVT_B, 256, 0, stream>>>(W1, W2, W3, src, dst, gcursor, epk, Wg8);
    k_passB<<<NBKT, 256, 0, stream>>>(epk, gcursor, rowptr, degp, dinv, esrc);

    // ---- layer 1 (dense), layers 2,3 (fused gather+gemm) ----
    k_gemm<true><<<GEMB, 256, 0, stream>>>(x, A8a, esrc, rowptr, degp, dinv, nullptr, Wg8, A8a);
    k_gemm<false><<<GEMB, 256, 0, stream>>>(nullptr, A8a, esrc, rowptr, degp, dinv, b1, Wg8 + 16384, A8b);
    k_gemm<false><<<GEMB, 256, 0, stream>>>(nullptr, A8b, esrc, rowptr, degp, dinv, b2, Wg8 + 32768, A8a);
    // ---- layer-3 gather + relu + pool ----
    k_gatherpool<<<NGATB, 256, 0, stream>>>(A8a, esrc, rowptr, degp, dinv, b3, ppart);

    k_red1<<<128, 128, 0, stream>>>(ppart, pp2);
    k_final<<<1, 128, 0, stream>>>(pp2, fcw, fcb, out);
}

// Round 13
// 196.773 us; speedup vs baseline: 1.6633x; 1.6633x over previous
//
#include <hip/hip_runtime.h>
#include <math.h>

#define NN 100000
#define NE 1600000
#define DIM 128
#define NBKT 196        // ceil(100000/512) coarse buckets (dst>>9)
#define BSTRIDE 9216    // per-bucket arena stride (mean 8163 + ~11 sigma)
#define PA_EPB 4096
#define PA_GRID ((NE + PA_EPB - 1) / PA_EPB)   // 391
#define GB 1563         // gemm blocks: ceil(NN/64)
#define WCVT_B 24       // 3 layers * 128 cols * 16 kchunks / 256
#define NGATB 3125      // gather grid: NN*8/256

typedef __attribute__((ext_vector_type(4))) float f32x4;
typedef __attribute__((ext_vector_type(2))) float f32x2;

__device__ __forceinline__ void accp8(unsigned int w, float* a) {
    f32x2 lo = __builtin_amdgcn_cvt_pk_f32_fp8(w, false);
    f32x2 hi = __builtin_amdgcn_cvt_pk_f32_fp8(w, true);
    a[0] += lo[0]; a[1] += lo[1]; a[2] += hi[0]; a[3] += hi[1];
}
__device__ __forceinline__ void unp8(unsigned int w, float* a) {
    f32x2 lo = __builtin_amdgcn_cvt_pk_f32_fp8(w, false);
    f32x2 hi = __builtin_amdgcn_cvt_pk_f32_fp8(w, true);
    a[0] = lo[0]; a[1] = lo[1]; a[2] = hi[0]; a[3] = hi[1];
}
__device__ __forceinline__ unsigned int pk4(float a, float b, float c, float d) {
    unsigned int w = __builtin_amdgcn_cvt_pk_fp8_f32(a, b, 0u, false);
    return __builtin_amdgcn_cvt_pk_fp8_f32(c, d, w, true);
}

// ---------------- init arena cursors ----------------
__global__ void k_initcur(int* __restrict__ gcursor) {
    int i = threadIdx.x;
    if (i < NBKT) gcursor[i] = i * BSTRIDE;
}

// =======================================================================
// k_pawc: [0,PA_GRID) CSR passA  |  [PA_GRID,+WCVT_B) W1/W2/W3 -> fp8 image
// fp8 W image layout (per layer, 16384 B): byte = col*128 + ((kc^(col&15))*8)
//   col&15 == l15 distinct per 16-lane MFMA group -> full 32-bank coverage
// =======================================================================
__global__ __launch_bounds__(256) void k_pawc(const float* __restrict__ W1,
                                              const float* __restrict__ W2,
                                              const float* __restrict__ W3,
                                              const int* __restrict__ src,
                                              const int* __restrict__ dst,
                                              int* __restrict__ gcursor,
                                              unsigned int* __restrict__ epk,
                                              char* __restrict__ Wg8) {
    __shared__ __align__(16) char smem[24768];
    const int tid = threadIdx.x;
    const int bid = blockIdx.x;

    if (bid < PA_GRID) {
        int* hist = (int*)smem;                         // 784 B
        int* offs = (int*)(smem + 784);
        int* gbase = (int*)(smem + 1568);
        int* lcur = (int*)(smem + 2352);
        int* sc   = (int*)(smem + 3136);                // 1024 B
        unsigned int* stg = (unsigned int*)(smem + 4160);     // 16 KB
        unsigned char* stgb = (unsigned char*)(smem + 20544); // 4 KB
        const int e0 = bid * PA_EPB;
        const int ecnt = min(PA_EPB, NE - e0);

        for (int i = tid; i < NBKT; i += 256) hist[i] = 0;
        __syncthreads();
        for (int i = tid; i < ecnt; i += 256)
            atomicAdd(&hist[dst[e0 + i] >> 9], 1);
        __syncthreads();
        int v = (tid < NBKT) ? hist[tid] : 0;
        sc[tid] = v;
        __syncthreads();
        for (int off = 1; off < 256; off <<= 1) {
            int t = (tid >= off) ? sc[tid - off] : 0;
            __syncthreads();
            sc[tid] += t;
            __syncthreads();
        }
        if (tid < NBKT) {
            offs[tid] = sc[tid] - v;
            lcur[tid] = sc[tid] - v;
            gbase[tid] = v ? atomicAdd(&gcursor[tid], v) : 0;
        }
        __syncthreads();
        for (int i = tid; i < ecnt; i += 256) {
            int d = dst[e0 + i];
            int s = src[e0 + i];
            int b = d >> 9;
            int pos = atomicAdd(&lcur[b], 1);
            stg[pos] = ((unsigned)(d & 511) << 17) | (unsigned)s;
            stgb[pos] = (unsigned char)b;
        }
        __syncthreads();
        for (int i = tid; i < ecnt; i += 256) {
            int b = stgb[i];
            epk[gbase[b] + (i - offs[b])] = stg[i];
        }
    } else {
        int idx2 = (bid - PA_GRID) * 256 + tid;   // 0 .. 6143
        if (idx2 < 3 * 2048) {
            int layer = idx2 >> 11, r = idx2 & 2047;
            const float* W = layer == 0 ? W1 : (layer == 1 ? W2 : W3);
            int col = r >> 4;    // 0..127
            int kc  = r & 15;    // k-chunk of 8
            uint2 d;
            d.x = pk4(W[(kc * 8 + 0) * DIM + col], W[(kc * 8 + 1) * DIM + col],
                      W[(kc * 8 + 2) * DIM + col], W[(kc * 8 + 3) * DIM + col]);
            d.y = pk4(W[(kc * 8 + 4) * DIM + col], W[(kc * 8 + 5) * DIM + col],
                      W[(kc * 8 + 6) * DIM + col], W[(kc * 8 + 7) * DIM + col]);
            *reinterpret_cast<uint2*>(Wg8 + layer * 16384 + col * 128 + ((kc ^ (col & 15)) * 8)) = d;
        }
    }
}

// ---------------- passB: per-bucket fine CSR (rowptr/deg/dinv + sorted esrc) ----------------
__global__ __launch_bounds__(256) void k_passB(const unsigned int* __restrict__ epk,
                                               const int* __restrict__ gcursor,
                                               int* __restrict__ rowptr,
                                               int* __restrict__ degp,
                                               float* __restrict__ dinv,
                                               int* __restrict__ esrc) {
    __shared__ int cnt[512];
    __shared__ int offs[512];
    __shared__ int lcur[512];
    __shared__ int sc[256];
    __shared__ int stg[BSTRIDE];
    const int b = blockIdx.x, tid = threadIdx.x;
    const int n0 = b << 9;
    const int nnb = min(512, NN - n0);
    const int ebase = b * BSTRIDE;
    const int ecnt = min(gcursor[b] - ebase, BSTRIDE);

    for (int i = tid; i < 512; i += 256) cnt[i] = 0;
    __syncthreads();
    for (int i = tid; i < ecnt; i += 256)
        atomicAdd(&cnt[epk[ebase + i] >> 17], 1);
    __syncthreads();
    int a0 = cnt[2 * tid], a1 = cnt[2 * tid + 1];
    sc[tid] = a0 + a1;
    __syncthreads();
    for (int off = 1; off < 256; off <<= 1) {
        int t = (tid >= off) ? sc[tid - off] : 0;
        __syncthreads();
        sc[tid] += t;
        __syncthreads();
    }
    int base = sc[tid] - (a0 + a1);
    offs[2 * tid] = base;
    offs[2 * tid + 1] = base + a0;
    lcur[2 * tid] = base;
    lcur[2 * tid + 1] = base + a0;
    __syncthreads();
    for (int ln = tid; ln < nnb; ln += 256) {
        int dg = cnt[ln];
        rowptr[n0 + ln] = ebase + offs[ln];
        degp[n0 + ln] = dg;
        dinv[n0 + ln] = rsqrtf(1.f + (float)dg);
    }
    for (int i = tid; i < ecnt; i += 256) {
        unsigned p = epk[ebase + i];
        int pos = atomicAdd(&lcur[p >> 17], 1);
        stg[pos] = (int)(p & 0x1FFFFu);
    }
    __syncthreads();
    for (int i = tid; i < ecnt; i += 256)
        esrc[ebase + i] = stg[i];
}

// =======================================================================
// k_aggemm<DENSE>: [gather prev-g + bias + relu | dense x read] -> fp8 X tile
//                  -> fp8 MFMA with fp8 W image -> *dinv -> fp8 g out
// LDS: Wt8 16 KB + Xb8 8 KB = 24 KB  (6 blocks/CU, 64 VGPR — round-10 config)
// =======================================================================
template <bool DENSE>
__global__ __launch_bounds__(256) void k_aggemm(const float* __restrict__ x,
                                                const uint4* __restrict__ g8,
                                                const int* __restrict__ esrc,
                                                const int* __restrict__ rowptr,
                                                const int* __restrict__ degp,
                                                const float* __restrict__ dinv,
                                                const float* __restrict__ bias,
                                                const char* __restrict__ Wgl,
                                                uint4* __restrict__ out8) {
    __shared__ __align__(16) char Wt8[16384];   // fp8 [col][k] swizzled (&15)
    __shared__ __align__(16) char Xb8[8192];    // fp8 [row][col] swizzled; reused as out stage
    const int tid = threadIdx.x;
    const int rb = blockIdx.x * 64;

    // stage pre-swizzled W image (pure copy)
    for (int idx = tid; idx < 1024; idx += 256)
        reinterpret_cast<uint4*>(Wt8)[idx] = reinterpret_cast<const uint4*>(Wgl)[idx];

    // ---- X phase: 32 groups x 8 lanes; 2 rows per group ----
    const int gid = tid >> 3;
    const int c = tid & 7;             // 16-col chunk
#pragma unroll
    for (int rr = 0; rr < 2; ++rr) {
        const int row = gid + rr * 32;
        const int grow = rb + row;
        uint4 o = make_uint4(0u, 0u, 0u, 0u);
        if (grow < NN) {
            float r[16];
            if (DENSE) {
                const float4* xp = reinterpret_cast<const float4*>(x + (size_t)grow * DIM + c * 16);
                float4 v0 = xp[0], v1 = xp[1], v2 = xp[2], v3 = xp[3];
                r[0] = v0.x;  r[1] = v0.y;  r[2] = v0.z;  r[3] = v0.w;
                r[4] = v1.x;  r[5] = v1.y;  r[6] = v1.z;  r[7] = v1.w;
                r[8] = v2.x;  r[9] = v2.y;  r[10] = v2.z; r[11] = v2.w;
                r[12] = v3.x; r[13] = v3.y; r[14] = v3.z; r[15] = v3.w;
            } else {
                float a[16];
                uint4 sv = g8[(size_t)grow * 8 + c];
                unp8(sv.x, a); unp8(sv.y, a + 4); unp8(sv.z, a + 8); unp8(sv.w, a + 12);
                int j0 = rowptr[grow];
                int j1 = j0 + degp[grow];
                int j = j0;
                for (; j + 4 <= j1; j += 4) {
                    int s0 = esrc[j], s1 = esrc[j + 1], s2 = esrc[j + 2], s3 = esrc[j + 3];
                    uint4 v0 = g8[(size_t)s0 * 8 + c];
                    uint4 v1 = g8[(size_t)s1 * 8 + c];
                    uint4 v2 = g8[(size_t)s2 * 8 + c];
                    uint4 v3 = g8[(size_t)s3 * 8 + c];
                    accp8(v0.x, a); accp8(v0.y, a + 4); accp8(v0.z, a + 8); accp8(v0.w, a + 12);
                    accp8(v1.x, a); accp8(v1.y, a + 4); accp8(v1.z, a + 8); accp8(v1.w, a + 12);
                    accp8(v2.x, a); accp8(v2.y, a + 4); accp8(v2.z, a + 8); accp8(v2.w, a + 12);
                    accp8(v3.x, a); accp8(v3.y, a + 4); accp8(v3.z, a + 8); accp8(v3.w, a + 12);
                }
                for (; j < j1; ++j) {
                    uint4 v = g8[(size_t)esrc[j] * 8 + c];
                    accp8(v.x, a); accp8(v.y, a + 4); accp8(v.z, a + 8); accp8(v.w, a + 12);
                }
                float di = dinv[grow];
                const float4* bp = reinterpret_cast<const float4*>(bias + c * 16);
#pragma unroll
                for (int q = 0; q < 4; ++q) {
                    float4 bb = bp[q];
                    r[q * 4 + 0] = fmaxf(fmaf(a[q * 4 + 0], di, bb.x), 0.f);
                    r[q * 4 + 1] = fmaxf(fmaf(a[q * 4 + 1], di, bb.y), 0.f);
                    r[q * 4 + 2] = fmaxf(fmaf(a[q * 4 + 2], di, bb.z), 0.f);
                    r[q * 4 + 3] = fmaxf(fmaf(a[q * 4 + 3], di, bb.w), 0.f);
                }
            }
            o.x = pk4(r[0], r[1], r[2], r[3]);
            o.y = pk4(r[4], r[5], r[6], r[7]);
            o.z = pk4(r[8], r[9], r[10], r[11]);
            o.w = pk4(r[12], r[13], r[14], r[15]);
        }
        // swizzled fp8 X store: 16B at [row][ (c^(row&7)) *16 ]
        *reinterpret_cast<uint4*>(&Xb8[row * 128 + ((c ^ (row & 7)) * 16)]) = o;
    }
    __syncthreads();

    // ---- MFMA phase (swapped operands: A=W-frag, B=X-frag => D[wcol][node]) ----
    const int lane = tid & 63;
    const int w    = tid >> 6;
    const int l15  = lane & 15;
    const int kg   = lane >> 4;
    f32x4 acc[8];
#pragma unroll
    for (int i = 0; i < 8; ++i) acc[i] = (f32x4){0.f, 0.f, 0.f, 0.f};
    const int arow = w * 16 + l15;
#pragma unroll
    for (int ks = 0; ks < 4; ++ks) {
        int kc = ks * 4 + kg;
        long xf = *reinterpret_cast<const long*>(
            &Xb8[arow * 128 + (((kc >> 1) ^ (arow & 7)) * 16 + (kc & 1) * 8)]);
#pragma unroll
        for (int ct = 0; ct < 8; ++ct) {
            int col = ct * 16 + l15;
            long wf = *reinterpret_cast<const long*>(&Wt8[col * 128 + ((kc ^ (col & 15)) * 8)]);
            acc[ct] = __builtin_amdgcn_mfma_f32_16x16x32_fp8_fp8(wf, xf, acc[ct], 0, 0, 0);
        }
    }
    __syncthreads();

    // ---- epilogue: *dinv, pack fp8, swizzled LDS stage, coalesced store ----
    unsigned int* Xo = reinterpret_cast<unsigned int*>(Xb8);
    const int node = w * 16 + l15;
    const int gnode = rb + node;
    float dv = (gnode < NN) ? dinv[gnode] : 0.f;
#pragma unroll
    for (int ct = 0; ct < 8; ++ct) {
        unsigned int d = pk4(acc[ct][0] * dv, acc[ct][1] * dv, acc[ct][2] * dv, acc[ct][3] * dv);
        Xo[node * 32 + ((ct * 4 + kg) ^ ((node & 7) << 2))] = d;
    }
    __syncthreads();
    for (int idx = tid; idx < 64 * 8; idx += 256) {
        int row = idx >> 3, kc = idx & 7;
        int grow = rb + row;
        if (grow < NN)
            out8[(size_t)grow * 8 + kc] =
                reinterpret_cast<const uint4*>(Xo)[row * 8 + (kc ^ (row & 7))];
    }
}

// ------- final gather + bias + relu + mean-pool partials -------
__global__ __launch_bounds__(256) void k_gatherpool(const uint4* __restrict__ g8,
                                                    const int* __restrict__ esrc,
                                                    const int* __restrict__ rowptr,
                                                    const int* __restrict__ degp,
                                                    const float* __restrict__ dinv,
                                                    const float* __restrict__ bias,
                                                    float* __restrict__ ppart) {
    int t = blockIdx.x * 256 + threadIdx.x;
    int n = t >> 3;
    int c = t & 7;
    int j0 = rowptr[n], j1 = j0 + degp[n];
    float a[16];
    uint4 sv = g8[(size_t)n * 8 + c];
    unp8(sv.x, a); unp8(sv.y, a + 4); unp8(sv.z, a + 8); unp8(sv.w, a + 12);
    int j = j0;
    for (; j + 4 <= j1; j += 4) {
        int s0 = esrc[j], s1 = esrc[j + 1], s2 = esrc[j + 2], s3 = esrc[j + 3];
        uint4 v0 = g8[(size_t)s0 * 8 + c];
        uint4 v1 = g8[(size_t)s1 * 8 + c];
        uint4 v2 = g8[(size_t)s2 * 8 + c];
        uint4 v3 = g8[(size_t)s3 * 8 + c];
        accp8(v0.x, a); accp8(v0.y, a + 4); accp8(v0.z, a + 8); accp8(v0.w, a + 12);
        accp8(v1.x, a); accp8(v1.y, a + 4); accp8(v1.z, a + 8); accp8(v1.w, a + 12);
        accp8(v2.x, a); accp8(v2.y, a + 4); accp8(v2.z, a + 8); accp8(v2.w, a + 12);
        accp8(v3.x, a); accp8(v3.y, a + 4); accp8(v3.z, a + 8); accp8(v3.w, a + 12);
    }
    for (; j < j1; ++j) {
        uint4 v = g8[(size_t)esrc[j] * 8 + c];
        accp8(v.x, a); accp8(v.y, a + 4); accp8(v.z, a + 8); accp8(v.w, a + 12);
    }
    float di = dinv[n];
    const float4* bp = reinterpret_cast<const float4*>(bias + c * 16);
    __shared__ float red[32][132];
    int slot = threadIdx.x >> 3;
#pragma unroll
    for (int q = 0; q < 4; ++q) {
        float4 bb = bp[q];
        red[slot][c * 16 + q * 4 + 0] = fmaxf(fmaf(a[q * 4 + 0], di, bb.x), 0.f);
        red[slot][c * 16 + q * 4 + 1] = fmaxf(fmaf(a[q * 4 + 1], di, bb.y), 0.f);
        red[slot][c * 16 + q * 4 + 2] = fmaxf(fmaf(a[q * 4 + 2], di, bb.z), 0.f);
        red[slot][c * 16 + q * 4 + 3] = fmaxf(fmaf(a[q * 4 + 3], di, bb.w), 0.f);
    }
    __syncthreads();
    if (threadIdx.x < 128) {
        float s = 0.f;
#pragma unroll
        for (int sl = 0; sl < 32; ++sl) s += red[sl][threadIdx.x];
        ppart[blockIdx.x * 128 + threadIdx.x] = s;
    }
}

// ---------------- pool partial reduce: 3125x128 -> 128x128 ----------------
__global__ void k_red1(const float* __restrict__ ppart, float* __restrict__ pp2) {
    int j = blockIdx.x;
    int c = threadIdx.x;
    int p0 = j * 25, p1 = min(p0 + 25, NGATB);
    float s = 0.f;
    for (int p = p0; p < p1; ++p) s += ppart[p * 128 + c];
    pp2[j * 128 + c] = s;
}

// ---------------- final: reduce + fc + softmax ----------------
__global__ void k_final(const float* __restrict__ pp2, const float* __restrict__ fc_w,
                        const float* __restrict__ fc_b, float* __restrict__ out) {
    __shared__ float part[4][DIM];
    int c = threadIdx.x;
    float s = 0.f;
    for (int j = 0; j < 128; ++j) s += pp2[j * 128 + c];
    float p = s * (1.f / NN);
    for (int j = 0; j < 4; ++j) part[j][c] = p * fc_w[c * 4 + j];
    __syncthreads();
    if (c == 0) {
        float l[4];
        for (int j = 0; j < 4; ++j) {
            float acc = fc_b[j];
            for (int i = 0; i < DIM; ++i) acc += part[j][i];
            l[j] = acc;
        }
        float m = fmaxf(fmaxf(l[0], l[1]), fmaxf(l[2], l[3]));
        float e[4], Z = 0.f;
        for (int j = 0; j < 4; ++j) { e[j] = expf(l[j] - m); Z += e[j]; }
        for (int j = 0; j < 4; ++j) out[j] = e[j] / Z;
    }
}

extern "C" void kernel_launch(void* const* d_in, const int* in_sizes, int n_in,
                              void* d_out, int out_size, void* d_ws, size_t ws_size,
                              hipStream_t stream) {
    const float* x   = (const float*)d_in[0];
    const int*   ei  = (const int*)d_in[1];
    const float* W1  = (const float*)d_in[2];
    const float* b1  = (const float*)d_in[3];
    const float* W2  = (const float*)d_in[4];
    const float* b2  = (const float*)d_in[5];
    const float* W3  = (const float*)d_in[6];
    const float* b3  = (const float*)d_in[7];
    const float* fcw = (const float*)d_in[8];
    const float* fcb = (const float*)d_in[9];
    float* out = (float*)d_out;

    char* ws = (char*)d_ws;
    uint4* A8a     = (uint4*)(ws);                       // 12,800,000 B (fp8 g)
    uint4* A8b     = (uint4*)(ws + 12800000);            // 12,800,000 B
    float* dinv    = (float*)(ws + 25600000);            //    400,000 B
    int*   rowptr  = (int*)  (ws + 26000000);            //    400,000 B
    int*   degp    = (int*)  (ws + 26400000);            //    400,000 B
    int*   esrc    = (int*)  (ws + 26800000);            //  7,225,344 B
    unsigned int* epk = (unsigned int*)(ws + 34025344);  //  7,225,344 B
    int*   gcursor = (int*)  (ws + 41250688);            //      1,024 B
    float* ppart   = (float*)(ws + 41251712);            //  1,600,000 B
    float* pp2     = (float*)(ws + 42851712);            //     65,536 B
    char*  Wg8     = (char*) (ws + 42917248);            //     49,152 B (3 fp8 W images)

    const int* src = ei;
    const int* dst = ei + NE;

    // ---- CSR build + W fp8 images ----
    k_initcur<<<1, 256, 0, stream>>>(gcursor);
    k_pawc<<<PA_GRID + WCVT_B, 256, 0, stream>>>(W1, W2, W3, src, dst, gcursor, epk, Wg8);
    k_passB<<<NBKT, 256, 0, stream>>>(epk, gcursor, rowptr, degp, dinv, esrc);

    // ---- layer 1 (dense), layers 2,3 (fused gather+gemm) ----
    k_aggemm<true><<<GB, 256, 0, stream>>>(x, A8a, esrc, rowptr, degp, dinv, b1, Wg8, A8a);
    k_aggemm<false><<<GB, 256, 0, stream>>>(nullptr, A8a, esrc, rowptr, degp, dinv, b1, Wg8 + 16384, A8b);
    k_aggemm<false><<<GB, 256, 0, stream>>>(nullptr, A8b, esrc, rowptr, degp, dinv, b2, Wg8 + 32768, A8a);
    // ---- layer-3 gather + relu + pool ----
    k_gatherpool<<<NGATB, 256, 0, stream>>>(A8a, esrc, rowptr, degp, dinv, b3, ppart);

    k_red1<<<128, 128, 0, stream>>>(ppart, pp2);
    k_final<<<1, 128, 0, stream>>>(pp2, fcw, fcb, out);
}